// Round 8
// baseline (506.769 us; speedup 1.0000x reference)
//
#include <hip/hip_runtime.h>

#define T_TOKENS 4096
#define DIM      1024
#define HID      4096
#define NE       8
#define TOPK     2
#define MAXT64   136   // sum_e ceil(cnt_e/64) <= 8192/64 + 7 = 135

typedef __attribute__((ext_vector_type(8))) short short8;
typedef __attribute__((ext_vector_type(4))) float f32x4;

__device__ __forceinline__ unsigned short f2bf(float f) {
    unsigned int u = __builtin_bit_cast(unsigned int, f);
    u += 0x7fffu + ((u >> 16) & 1u);
    return (unsigned short)(u >> 16);
}

__device__ __forceinline__ void gload16(const void* g, void* l) {
    __builtin_amdgcn_global_load_lds(
        (const __attribute__((address_space(1))) unsigned int*)g,
        (__attribute__((address_space(3))) unsigned int*)l, 16, 0, 0);
}

// ------- prep: router (logits->top2->softmax->scatter) + x->bf16 + out=x -----
__global__ void prep_kernel(const float* __restrict__ x, const float* __restrict__ Wg,
                            const float* __restrict__ bg, int* __restrict__ counts,
                            int* __restrict__ rowlist, float* __restrict__ gatelist,
                            unsigned short* __restrict__ xb, float* __restrict__ out) {
    const int wid  = threadIdx.x >> 6;
    const int lane = threadIdx.x & 63;
    const int t = blockIdx.x * 4 + wid;
    float acc[NE];
#pragma unroll
    for (int e = 0; e < NE; ++e) acc[e] = 0.f;
    const float* xr = x + (size_t)t * DIM;
    for (int d = lane; d < DIM; d += 64) {
        const float xv = xr[d];
        const float* wr = Wg + (size_t)d * NE;
#pragma unroll
        for (int e = 0; e < NE; ++e) acc[e] += xv * wr[e];
    }
#pragma unroll
    for (int off = 32; off > 0; off >>= 1) {
#pragma unroll
        for (int e = 0; e < NE; ++e) acc[e] += __shfl_xor(acc[e], off);
    }
    if (lane == 0) {
        float lg[NE];
#pragma unroll
        for (int e = 0; e < NE; ++e) lg[e] = acc[e] + bg[e];
        int i1 = 0; float v1 = lg[0];
#pragma unroll
        for (int e = 1; e < NE; ++e) if (lg[e] > v1) { v1 = lg[e]; i1 = e; }
        int i2 = -1; float v2 = -3.4e38f;
#pragma unroll
        for (int e = 0; e < NE; ++e) if (e != i1 && lg[e] > v2) { v2 = lg[e]; i2 = e; }
        const float ex = expf(v2 - v1);            // v1 >= v2
        const float g1 = 1.f / (1.f + ex);
        const float g2 = ex / (1.f + ex);
        int p1 = atomicAdd(&counts[i1], 1);
        rowlist[i1 * T_TOKENS + p1] = t * 2;
        gatelist[i1 * T_TOKENS + p1] = g1;
        int p2 = atomicAdd(&counts[i2], 1);
        rowlist[i2 * T_TOKENS + p2] = t * 2 + 1;
        gatelist[i2 * T_TOKENS + p2] = g2;
    }
    // x -> bf16 copy + residual init (row is hot in L1)
    const float4* xr4 = (const float4*)xr;
    float4* o4 = (float4*)(out + (size_t)t * DIM);
    ushort4* xb4 = (ushort4*)(xb + (size_t)t * DIM);
#pragma unroll
    for (int p = 0; p < 4; ++p) {
        const int i = p * 64 + lane;
        const float4 v = xr4[i];
        o4[i] = v;
        ushort4 o;
        o.x = f2bf(v.x); o.y = f2bf(v.y); o.z = f2bf(v.z); o.w = f2bf(v.w);
        xb4[i] = o;
    }
}

// -------- planner: per-phase worklists ordered [e][colt][rt] ----------------
// Encoding: (e<<20) | (colt<<8) | rt    (64-row tiles, 64-col panels)
__global__ void planner_kernel(const int* __restrict__ counts, int* __restrict__ wl1,
                               int* __restrict__ wl2, int* __restrict__ nw) {
    __shared__ int tiles[NE], pref[NE + 1];
    const int tid = threadIdx.x;
    if (tid == 0) {
        int p = 0;
        for (int e = 0; e < NE; ++e) {
            tiles[e] = (counts[e] + 63) >> 6;
            pref[e] = p;
            p += tiles[e];
        }
        pref[NE] = p;
        nw[0] = p * (HID / 64);   // phase 1: 64 col-panels
        nw[1] = p * (DIM / 64);   // phase 2: 16 col-panels
    }
    __syncthreads();
    const int n1 = pref[NE] * (HID / 64), n2 = pref[NE] * (DIM / 64);
    for (int i = tid; i < n1; i += 256) {
        int e = 0;
        while (pref[e + 1] * (HID / 64) <= i) ++e;
        const int rel = i - pref[e] * (HID / 64);
        const int colt = rel / tiles[e];
        const int rt = rel - colt * tiles[e];
        wl1[i] = (e << 20) | (colt << 8) | rt;
    }
    for (int i = tid; i < n2; i += 256) {
        int e = 0;
        while (pref[e + 1] * (DIM / 64) <= i) ++e;
        const int rel = i - pref[e] * (DIM / 64);
        const int colt = rel / tiles[e];
        const int rt = rel - colt * tiles[e];
        wl2[i] = (e << 20) | (colt << 8) | rt;
    }
}

// ---------------- W [e][K][N] f32 -> Wb [e][N][K] bf16 (transpose-convert) ---
template <int K, int N>
__global__ __launch_bounds__(256) void transconv_kernel(const float* __restrict__ W,
                                                        unsigned short* __restrict__ Wb) {
    const int e  = blockIdx.z;
    const int k0 = blockIdx.y * 64;
    const int nb = blockIdx.x * 64;
    __shared__ unsigned short t[64][72];
    const int tid = threadIdx.x;
    const int r  = tid >> 4;
    const int c4 = (tid & 15) * 4;
    const float* src = W + (size_t)e * K * N + (size_t)(k0 + r) * N + nb + c4;
#pragma unroll
    for (int p = 0; p < 4; ++p) {
        const float4 v = *(const float4*)(src + (size_t)p * 16 * N);
        ushort4 o;
        o.x = f2bf(v.x); o.y = f2bf(v.y); o.z = f2bf(v.z); o.w = f2bf(v.w);
        *(ushort4*)(&t[r + p * 16][c4]) = o;
    }
    __syncthreads();
#pragma unroll
    for (int p = 0; p < 4; ++p) {
        const int n  = (tid >> 4) + p * 16;
        const int kk = (tid & 15) * 4;
        ushort4 o;
        o.x = t[kk][n]; o.y = t[kk + 1][n]; o.z = t[kk + 2][n]; o.w = t[kk + 3][n];
        *(ushort4*)(Wb + (size_t)e * N * K + (size_t)(nb + n) * K + k0 + kk) = o;
    }
}

// ---- grouped GEMM, 64x64 tile, BK=64, 4 waves (2x2 of 32x32), high-occ -----
// PHASE 1: h[rid] = gelu(x[rid>>1] @ W1[e] + b1[e])
// PHASE 2: out[rid>>1] += gate * (h[rid] @ W2[e] + b2[e])   (atomic)
// Small acc (acc[2][2]=16 VGPR) -> ~6 blocks/CU resident: cross-block TLP
// hides the per-step vmcnt(0) drain (round-2 regime + round-7 locality).
// Worklist [e][colt][rt] XCD-chunked: consecutive rt reuse the 128KB B-panel
// in the XCD's L2. LDS [64][64] linear; 3-bit XOR granule swizzle on global
// source AND ds_read side (round-7 scheme, measured 0 conflicts).
template <int PHASE>
__global__ __launch_bounds__(256, 6) void moe_gemm(
    const unsigned short* __restrict__ A, const unsigned short* __restrict__ Wb,
    const float* __restrict__ bias, const int* __restrict__ counts,
    const int* __restrict__ rowlist, const float* __restrict__ gatelist,
    const int* __restrict__ wl, const int* __restrict__ nw,
    unsigned short* __restrict__ h, float* __restrict__ out) {
    constexpr int K = (PHASE == 1) ? DIM : HID;
    constexpr int N = (PHASE == 1) ? HID : DIM;
    constexpr int NT = K / 64;        // K-steps
    // --- XCD-chunked work assignment ---
    const int nwork = nw[PHASE - 1];
    const int chunk = (nwork + 7) >> 3;
    const int pos = blockIdx.x >> 3;
    if (pos >= chunk) return;
    const int widx = (blockIdx.x & 7) * chunk + pos;
    if (widx >= nwork) return;
    const int w = wl[widx];
    const int e    = w >> 20;
    const int colt = (w >> 8) & 0xfff;
    const int rt   = w & 0xff;
    const int cnt  = counts[e];
    const int n0   = colt * 64;

    __shared__ __align__(16) unsigned short As[64][64];   // 8 KB
    __shared__ __align__(16) unsigned short Bs[64][64];   // 8 KB
    __shared__ int rows_s[64];
    __shared__ float gates_s[64];

    const int tid = threadIdx.x;
    if (tid < 64) {
        const int gr = rt * 64 + tid;
        const int src = e * T_TOKENS + ((gr < cnt) ? gr : 0);
        rows_s[tid] = rowlist[src];
        gates_s[tid] = (gr < cnt) ? gatelist[src] : 0.f;
    }
    __syncthreads();

    const int lane = tid & 63;
    const int wv = tid >> 6;       // 4 waves

    // --- staging: per K-step each wave issues 2 A + 2 B gload16.
    // instr j of wave wv covers rows [(wv*2+j)*8, +8): lane l -> row +(l>>3),
    // LDS granule l&7 (linear dest). Source granule pre-swizzled (l&7)^(l>>3).
    const int rowin = lane >> 3;                      // 0..7
    const int kofs = ((lane & 7) ^ rowin) * 8;        // swizzled source k-elems
    const unsigned short* sA[2];
    const unsigned short* sB[2];
    int dLds[2];
#pragma unroll
    for (int j = 0; j < 2; ++j) {
        const int r = (wv * 2 + j) * 8 + rowin;
        const int rid = rows_s[r];
        sA[j] = A + (size_t)((PHASE == 1) ? (rid >> 1) : rid) * K + kofs;
        sB[j] = Wb + (size_t)e * N * K + (size_t)(n0 + r) * K + kofs;
        dLds[j] = (wv * 2 + j) * 8 * 64;              // elements
    }

    const int wr = wv >> 1;   // 2x2 waves, each owns 32x32
    const int wc = wv & 1;
    const int r15 = lane & 15;
    const int hi = lane >> 4;     // 0..3
    const int x7 = lane & 7;

    f32x4 acc[2][2];
#pragma unroll
    for (int m = 0; m < 2; ++m)
#pragma unroll
        for (int n = 0; n < 2; ++n)
#pragma unroll
            for (int r = 0; r < 4; ++r) acc[m][n][r] = 0.f;

    for (int t = 0; t < NT; ++t) {
        const int ko = t * 64;
#pragma unroll
        for (int j = 0; j < 2; ++j) gload16(sA[j] + ko, &As[0][0] + dLds[j]);
#pragma unroll
        for (int j = 0; j < 2; ++j) gload16(sB[j] + ko, &Bs[0][0] + dLds[j]);
        __syncthreads();   // compiler drains vmcnt(0) -> staged data visible

#pragma unroll
        for (int kk = 0; kk < 2; ++kk) {
            // frag read: granule (kk*4+hi) of row R stored at granule^(R&7),
            // R&7 == lane&7 (row-bases are multiples of 16)
            const int gsw = ((kk * 4 + hi) ^ x7) * 8;
            short8 af[2], bfr[2];
#pragma unroll
            for (int m = 0; m < 2; ++m)
                af[m] = *(const short8*)(&As[wr * 32 + m * 16 + r15][0] + gsw);
#pragma unroll
            for (int n = 0; n < 2; ++n)
                bfr[n] = *(const short8*)(&Bs[wc * 32 + n * 16 + r15][0] + gsw);
#pragma unroll
            for (int m = 0; m < 2; ++m)
#pragma unroll
                for (int n = 0; n < 2; ++n)
                    acc[m][n] = __builtin_amdgcn_mfma_f32_16x16x32_bf16(af[m], bfr[n], acc[m][n], 0, 0, 0);
        }
        __syncthreads();   // all reads done before next-iter staging overwrites
    }

    // epilogue: C/D layout col=lane&15, row=(lane>>4)*4+r
#pragma unroll
    for (int n = 0; n < 2; ++n) {
        const int col = n0 + wc * 32 + n * 16 + r15;
        const float bv = bias[(size_t)e * N + col];
#pragma unroll
        for (int m = 0; m < 2; ++m) {
            const int rbase = wr * 32 + m * 16 + hi * 4;
#pragma unroll
            for (int r = 0; r < 4; ++r) {
                const int row = rbase + r;
                if (rt * 64 + row < cnt) {
                    if (PHASE == 1) {
                        const float v = acc[m][n][r] + bv;
                        // tanh-approx gelu == v * sigmoid(1.5957691*(v+0.044715 v^3))
                        const float s = 1.f / (1.f + __expf(-1.5957691216f * (v + 0.044715f * v * v * v)));
                        h[(size_t)rows_s[row] * HID + col] = f2bf(v * s);
                    } else {
                        const float v = (acc[m][n][r] + bv) * gates_s[row];
                        atomicAdd(&out[(size_t)(rows_s[row] >> 1) * DIM + col], v);
                    }
                }
            }
        }
    }
}

extern "C" void kernel_launch(void* const* d_in, const int* in_sizes, int n_in,
                              void* d_out, int out_size, void* d_ws, size_t ws_size,
                              hipStream_t stream) {
    (void)in_sizes; (void)n_in; (void)out_size; (void)ws_size;
    const float* x  = (const float*)d_in[0];
    const float* Wg = (const float*)d_in[1];
    const float* bg = (const float*)d_in[2];
    const float* W1 = (const float*)d_in[3];
    const float* b1 = (const float*)d_in[4];
    const float* W2 = (const float*)d_in[5];
    const float* b2 = (const float*)d_in[6];
    float* out = (float*)d_out;

    char* ws = (char*)d_ws;
    size_t off = 0;
    auto alloc = [&](size_t bytes) -> void* {
        size_t a = (off + 255) & ~(size_t)255;
        off = a + bytes;
        return (void*)(ws + a);
    };
    int*   counts   = (int*)alloc(NE * sizeof(int));
    int*   nw       = (int*)alloc(2 * sizeof(int));
    int*   wl1      = (int*)alloc((size_t)MAXT64 * (HID / 64) * sizeof(int));
    int*   wl2      = (int*)alloc((size_t)MAXT64 * (DIM / 64) * sizeof(int));
    int*   rowlist  = (int*)alloc((size_t)NE * T_TOKENS * sizeof(int));
    float* gatelist = (float*)alloc((size_t)NE * T_TOKENS * sizeof(float));
    unsigned short* xb  = (unsigned short*)alloc((size_t)T_TOKENS * DIM * 2);
    unsigned short* h   = (unsigned short*)alloc((size_t)T_TOKENS * TOPK * HID * 2);
    unsigned short* W1b = (unsigned short*)alloc((size_t)NE * DIM * HID * 2);
    unsigned short* W2b = (unsigned short*)alloc((size_t)NE * HID * DIM * 2);
    // total ws use: ~200.4 MB

    hipMemsetAsync(counts, 0, NE * sizeof(int), stream);
    prep_kernel<<<T_TOKENS / 4, 256, 0, stream>>>(x, Wg, bg, counts, rowlist, gatelist, xb, out);
    planner_kernel<<<1, 256, 0, stream>>>(counts, wl1, wl2, nw);
    transconv_kernel<DIM, HID><<<dim3(HID / 64, DIM / 64, NE), 256, 0, stream>>>(W1, W1b);
    transconv_kernel<HID, DIM><<<dim3(DIM / 64, HID / 64, NE), 256, 0, stream>>>(W2, W2b);
    // phase 1: <= 136*64 = 8704 blocks (~8448 active), ~33 blocks/CU queued
    moe_gemm<1><<<MAXT64 * (HID / 64), 256, 0, stream>>>(
        xb, W1b, b1, counts, rowlist, gatelist, wl1, nw, h, nullptr);
    // phase 2: <= 136*16 = 2176 blocks (~2112 active)
    moe_gemm<2><<<MAXT64 * (DIM / 64), 256, 0, stream>>>(
        h, W2b, b2, counts, rowlist, gatelist, wl2, nw, nullptr, out);
}